// Round 1
// 1572.455 us; speedup vs baseline: 1.2715x; 1.2715x over previous
//
#include <hip/hip_runtime.h>
#include <math.h>

// ExpertChoice: B=1024, N=E=8, D=768, K=4, KD=3072, ND=6144, NC=1000
// v2: weights pre-converted fp32->bf16 + transposed to [N,K] (BW-bound pass),
//     GEMM rebuilt on global_load_lds(16B) + XOR-swizzled LDS (m97-class).

#define B_  1024
#define N_  8
#define E_  8
#define D_  768
#define KD_ 3072
#define ND_ 6144
#define NC_ 1000

typedef __attribute__((ext_vector_type(8))) short v8s;   // 8 bf16 = 4 VGPRs
typedef __attribute__((ext_vector_type(4))) float v4f;

__device__ __forceinline__ float gelu_f(float x) {
    return 0.5f * x * (1.0f + erff(x * 0.70710678118654752f));
}

__device__ __forceinline__ void gload_lds16(const void* g, void* l) {
    __builtin_amdgcn_global_load_lds(
        (const __attribute__((address_space(1))) unsigned int*)g,
        (__attribute__((address_space(3))) unsigned int*)l, 16, 0, 0);
}

// ---------------- router + gather + x->bf16 ----------------
__global__ __launch_bounds__(256) void router_gather(
    const float* __restrict__ x, const float* __restrict__ emb,
    __bf16* __restrict__ sel, __bf16* __restrict__ xbf)
{
    int wid  = blockIdx.x * 4 + (threadIdx.x >> 6);
    int lane = threadIdx.x & 63;
    int b = wid >> 3, n = wid & 7;
    const float* xr = x + ((size_t)b * N_ + n) * D_;

    double lg[E_];
    #pragma unroll
    for (int e = 0; e < E_; ++e) {
        const float* er = emb + e * D_;
        double acc = 0.0;
        for (int d = lane; d < D_; d += 64)
            acc += (double)xr[d] * (double)er[d];
        #pragma unroll
        for (int off = 32; off > 0; off >>= 1)
            acc += __shfl_xor(acc, off, 64);
        lg[e] = acc;
    }
    unsigned used = 0;
    int idx[4];
    #pragma unroll
    for (int j = 0; j < 4; ++j) {
        int bi = -1; double bv = 0.0;
        #pragma unroll
        for (int e = 0; e < E_; ++e) {
            if (!(used & (1u << e)) && (bi < 0 || lg[e] > bv)) { bv = lg[e]; bi = e; }
        }
        used |= 1u << bi; idx[j] = bi;
    }
    __bf16* dst = sel + ((size_t)n * B_ + b) * KD_;
    #pragma unroll
    for (int j = 0; j < 4; ++j) {
        const float* src = x + ((size_t)b * N_ + idx[j]) * D_;
        for (int d = lane; d < D_; d += 64)
            dst[j * D_ + d] = (__bf16)src[d];
    }
    __bf16* xd = xbf + (size_t)b * ND_ + n * D_;
    for (int d = lane; d < D_; d += 64) xd[d] = (__bf16)xr[d];
}

// ---------------- weight convert+transpose: Wt[n][k] bf16 = W[k][n] f32 ----------------
// zero-fills rows n in [N, Npad). 64x64 tiles via LDS.
__global__ __launch_bounds__(256) void wconv_t(
    const float* __restrict__ W, __bf16* __restrict__ Wt,
    int K, int N, int Npad)
{
    __shared__ __attribute__((aligned(16))) __bf16 t[64][72];
    const int bz = blockIdx.z;
    const float* Wb = W + (size_t)bz * K * N;
    __bf16* Wtb = Wt + (size_t)bz * Npad * K;
    const int k0 = blockIdx.x * 64, n0 = blockIdx.y * 64;
    const int tid = threadIdx.x;
    const int c4 = (tid & 15) * 4;      // n within tile
    const int r  = tid >> 4;            // k within tile (16 rows/pass)
    #pragma unroll
    for (int i = 0; i < 4; ++i) {
        int rr = r + i * 16;
        size_t gk = (size_t)(k0 + rr);
        int gn = n0 + c4;
        float v0 = 0.f, v1 = 0.f, v2 = 0.f, v3 = 0.f;
        if (gn + 4 <= N) {
            float4 v = *(const float4*)&Wb[gk * N + gn];
            v0 = v.x; v1 = v.y; v2 = v.z; v3 = v.w;
        } else {
            if (gn + 0 < N) v0 = Wb[gk * N + gn + 0];
            if (gn + 1 < N) v1 = Wb[gk * N + gn + 1];
            if (gn + 2 < N) v2 = Wb[gk * N + gn + 2];
            if (gn + 3 < N) v3 = Wb[gk * N + gn + 3];
        }
        t[c4 + 0][rr] = (__bf16)v0;
        t[c4 + 1][rr] = (__bf16)v1;
        t[c4 + 2][rr] = (__bf16)v2;
        t[c4 + 3][rr] = (__bf16)v3;
    }
    __syncthreads();
    const int n  = tid >> 2;            // 0..63
    const int kc = (tid & 3) * 16;      // 0,16,32,48
    uint4 a = *(const uint4*)&t[n][kc];
    uint4 b = *(const uint4*)&t[n][kc + 8];
    __bf16* op = Wtb + (size_t)(n0 + n) * K + (k0 + kc);
    *(uint4*)op       = a;
    *(uint4*)(op + 8) = b;
}

// ---------------- GEMM: C = act(A @ Bt^T + bias) ----------------
// A: [M,K] bf16 row-major; Bt: [Npad,K] bf16 row-major (K-contiguous).
// 128x128 tile, BK=64, 4 waves (64x64 each, 4x4 frags of mfma_16x16x32_bf16).
// Staging: global_load_lds width-16, linear LDS dest; granule XOR-swizzle
// (gp = glogical ^ (row&7)) applied on SOURCE addr and on ds_read (rule #21)
// -> fragment reads are 2-way (free) instead of 16-way conflicted.
template<bool GELU, bool OUT_BF16>
__global__ __launch_bounds__(256, 2) void gemm_bt(
    const __bf16* __restrict__ Ag, const __bf16* __restrict__ Btg,
    const float* __restrict__ biasg, void* __restrict__ Cg,
    int M, int N, int K,
    long long sA, long long sB, long long sBias, long long sC)
{
    const int bz = blockIdx.z;
    const __bf16* A  = Ag  + (size_t)bz * sA;
    const __bf16* Bt = Btg + (size_t)bz * sB;
    const float* bias = biasg + (size_t)bz * sBias;

    __shared__ __attribute__((aligned(16))) __bf16 As[128 * 64];   // 16 KB
    __shared__ __attribute__((aligned(16))) __bf16 Bs[128 * 64];   // 16 KB

    const int tid  = threadIdx.x;
    const int lane = tid & 63;
    const int g    = lane >> 4;
    const int l16  = lane & 15;
    const int wave = tid >> 6;
    const int m0 = blockIdx.y * 128;
    const int n0 = blockIdx.x * 128;
    const int wm = (wave >> 1) * 64;
    const int wn = (wave & 1) * 64;

    // staging slots: tt = tid + i*256 covers 1024 granules of 16B per tile
    const __bf16* pa[4];
    const __bf16* pb[4];
    __bf16* la[4];
    __bf16* lb[4];
    #pragma unroll
    for (int i = 0; i < 4; ++i) {
        int tt  = tid + i * 256;
        int row = tt >> 3;                      // LDS row 0..127
        int gl  = (tt & 7) ^ (row & 7);         // logical granule for this slot
        pa[i] = A  + (size_t)(m0 + row) * K + gl * 8;
        pb[i] = Bt + (size_t)(n0 + row) * K + gl * 8;
        la[i] = &As[tt * 8];
        lb[i] = &Bs[tt * 8];
    }

    // fragment read bases (element offsets); row&7 == l16&7 for all frags
    int raA[4], raB[4];
    #pragma unroll
    for (int i = 0; i < 4; ++i) {
        raA[i] = (wm + i * 16 + l16) * 64;
        raB[i] = (wn + i * 16 + l16) * 64;
    }
    const int swz = l16 & 7;

    v4f acc[4][4] = {};

    const int kIters = K >> 6;
    for (int kt = 0; kt < kIters; ++kt) {
        __syncthreads();                        // prev tile's frags consumed
        #pragma unroll
        for (int i = 0; i < 4; ++i) gload_lds16(pa[i], la[i]);
        #pragma unroll
        for (int i = 0; i < 4; ++i) gload_lds16(pb[i], lb[i]);
        #pragma unroll
        for (int i = 0; i < 4; ++i) { pa[i] += 64; pb[i] += 64; }
        __syncthreads();                        // vmcnt(0) drain -> tile ready

        #pragma unroll
        for (int h = 0; h < 2; ++h) {
            const int gp8 = ((((h << 2) + g) ^ swz) << 3);
            v8s af[4], bfr[4];
            #pragma unroll
            for (int mi = 0; mi < 4; ++mi)
                af[mi] = *(const v8s*)&As[raA[mi] + gp8];
            #pragma unroll
            for (int ni = 0; ni < 4; ++ni)
                bfr[ni] = *(const v8s*)&Bs[raB[ni] + gp8];
            #pragma unroll
            for (int mi = 0; mi < 4; ++mi)
                #pragma unroll
                for (int ni = 0; ni < 4; ++ni)
                    acc[mi][ni] = __builtin_amdgcn_mfma_f32_16x16x32_bf16(
                        af[mi], bfr[ni], acc[mi][ni], 0, 0, 0);
        }
    }

    // epilogue: C/D layout col=lane&15, row=(lane>>4)*4+r (m89-verified)
    #pragma unroll
    for (int mi = 0; mi < 4; ++mi) {
        #pragma unroll
        for (int ni = 0; ni < 4; ++ni) {
            int col = n0 + wn + ni * 16 + l16;
            if (col < N) {
                float bc = bias[col];
                #pragma unroll
                for (int r = 0; r < 4; ++r) {
                    int row = m0 + wm + mi * 16 + g * 4 + r;
                    float v = acc[mi][ni][r] + bc;
                    if (GELU) v = gelu_f(v);
                    if (OUT_BF16)
                        ((__bf16*)Cg)[(size_t)bz * sC + (size_t)row * N + col] = (__bf16)v;
                    else
                        ((float*)Cg)[(size_t)bz * sC + (size_t)row * N + col] = v;
                }
            }
        }
    }
}

// ---------------- sw fc2: wlog[b,e] = Hs[b,:] . swW2[:,e] + swb2[e] ----------------
__global__ __launch_bounds__(256) void sw_fc2(
    const __bf16* __restrict__ Hs, const float* __restrict__ swW2,
    const float* __restrict__ swb2, float* __restrict__ wlog)
{
    int wid  = blockIdx.x * 4 + (threadIdx.x >> 6);
    int lane = threadIdx.x & 63;
    int b = wid >> 3, e = wid & 7;
    const __bf16* hr = Hs + (size_t)b * ND_;
    float acc = 0.f;
    for (int i = lane; i < ND_; i += 64)
        acc += (float)hr[i] * swW2[(size_t)i * E_ + e];
    #pragma unroll
    for (int off = 32; off > 0; off >>= 1)
        acc += __shfl_xor(acc, off, 64);
    if (lane == 0) wlog[b * E_ + e] = acc + swb2[e];
}

// ---------------- softmax(wlog) + combine ----------------
__global__ __launch_bounds__(256) void combine_ws(
    const __bf16* __restrict__ ER, const float* __restrict__ wlog,
    __bf16* __restrict__ ws)
{
    int b = blockIdx.y;
    int k = blockIdx.x * 256 + threadIdx.x;
    float l[E_];
    float mx = -1e30f;
    #pragma unroll
    for (int e = 0; e < E_; ++e) { l[e] = wlog[b * E_ + e]; mx = fmaxf(mx, l[e]); }
    float s = 0.f;
    #pragma unroll
    for (int e = 0; e < E_; ++e) { l[e] = expf(l[e] - mx); s += l[e]; }
    float inv = 1.0f / s;
    float acc = 0.f;
    #pragma unroll
    for (int e = 0; e < E_; ++e)
        acc += (float)ER[((size_t)e * B_ + b) * KD_ + k] * l[e];
    ws[(size_t)b * KD_ + k] = (__bf16)(acc * inv);
}

extern "C" void kernel_launch(void* const* d_in, const int* in_sizes, int n_in,
                              void* d_out, int out_size, void* d_ws, size_t ws_size,
                              hipStream_t stream)
{
    const float* x    = (const float*)d_in[0];
    const float* emb  = (const float*)d_in[1];
    const float* W1   = (const float*)d_in[2];
    const float* b1   = (const float*)d_in[3];
    const float* W2   = (const float*)d_in[4];
    const float* b2   = (const float*)d_in[5];
    const float* swW1 = (const float*)d_in[6];
    const float* swb1 = (const float*)d_in[7];
    const float* swW2 = (const float*)d_in[8];
    const float* swb2 = (const float*)d_in[9];
    const float* chW1 = (const float*)d_in[10];
    const float* chb1 = (const float*)d_in[11];
    const float* chW2 = (const float*)d_in[12];
    const float* chb2 = (const float*)d_in[13];

    char* wsp = (char*)d_ws;
    size_t off = 0;
    auto alloc = [&](size_t bytes) -> void* {
        void* p = wsp + off;
        off = (off + bytes + 255) & ~(size_t)255;
        return p;
    };
    __bf16* sel  = (__bf16*)alloc((size_t)E_ * B_ * KD_ * 2);  // later reused as ER
    __bf16* H    = (__bf16*)alloc((size_t)E_ * B_ * KD_ * 2);
    __bf16* xbf  = (__bf16*)alloc((size_t)B_ * ND_ * 2);
    __bf16* Hs   = (__bf16*)alloc((size_t)B_ * ND_ * 2);
    float*  wlog = (float*)alloc((size_t)B_ * E_ * 4);
    __bf16* wsb  = (__bf16*)alloc((size_t)B_ * KD_ * 2);
    __bf16* T    = (__bf16*)alloc((size_t)B_ * KD_ * 2);
    __bf16* Wt   = (__bf16*)alloc((size_t)4 * KD_ * KD_ * 2);  // 75.5 MB, reused
    __bf16* ER   = sel;   // sel dead after fc1 (kernel-boundary ordered)

    router_gather<<<dim3(B_ * N_ / 4), 256, 0, stream>>>(x, emb, sel, xbf);

    // expert fc1: H = gelu(sel @ W1 + b1)  — two 4-expert batches through Wt
    for (int hb = 0; hb < 2; ++hb) {
        size_t eo = (size_t)hb * 4;
        wconv_t<<<dim3(48, 48, 4), 256, 0, stream>>>(
            W1 + eo * KD_ * KD_, Wt, KD_, KD_, KD_);
        gemm_bt<true, true><<<dim3(24, 8, 4), 256, 0, stream>>>(
            sel + eo * B_ * KD_, Wt, b1 + eo * KD_, H + eo * B_ * KD_,
            B_, KD_, KD_,
            (long long)B_ * KD_, (long long)KD_ * KD_, (long long)KD_, (long long)B_ * KD_);
    }
    // expert fc2: ER = H @ W2 + b2
    for (int hb = 0; hb < 2; ++hb) {
        size_t eo = (size_t)hb * 4;
        wconv_t<<<dim3(48, 48, 4), 256, 0, stream>>>(
            W2 + eo * KD_ * KD_, Wt, KD_, KD_, KD_);
        gemm_bt<false, true><<<dim3(24, 8, 4), 256, 0, stream>>>(
            H + eo * B_ * KD_, Wt, b2 + eo * KD_, ER + eo * B_ * KD_,
            B_, KD_, KD_,
            (long long)B_ * KD_, (long long)KD_ * KD_, (long long)KD_, (long long)B_ * KD_);
    }
    // sw fc1: Hs = gelu(xbf @ swW1 + swb1)
    wconv_t<<<dim3(96, 96, 1), 256, 0, stream>>>(swW1, Wt, ND_, ND_, ND_);
    gemm_bt<true, true><<<dim3(48, 8, 1), 256, 0, stream>>>(
        xbf, Wt, swb1, Hs, B_, ND_, ND_, 0, 0, 0, 0);
    sw_fc2<<<dim3(B_ * E_ / 4), 256, 0, stream>>>(Hs, swW2, swb2, wlog);
    combine_ws<<<dim3(KD_ / 256, B_), 256, 0, stream>>>(ER, wlog, wsb);
    // head fc1: T = gelu(wsb @ chW1 + chb1)
    wconv_t<<<dim3(48, 48, 1), 256, 0, stream>>>(chW1, Wt, KD_, KD_, KD_);
    gemm_bt<true, true><<<dim3(24, 8, 1), 256, 0, stream>>>(
        wsb, Wt, chb1, T, B_, KD_, KD_, 0, 0, 0, 0);
    // head fc2: out = T @ chW2 + chb2  (N=1000, Bt padded to 1024 rows, zero-filled)
    wconv_t<<<dim3(48, 16, 1), 256, 0, stream>>>(chW2, Wt, KD_, NC_, 1024);
    gemm_bt<false, false><<<dim3(8, 8, 1), 256, 0, stream>>>(
        T, Wt, chb2, (float*)d_out, B_, NC_, KD_, 0, 0, 0, 0);
}